// Round 15
// baseline (192.564 us; speedup 1.0000x reference)
//
#include <hip/hip_runtime.h>
#include <hip/hip_fp16.h>

typedef _Float16 half8 __attribute__((ext_vector_type(8)));
typedef float f32x4 __attribute__((ext_vector_type(4)));

#define NXCD 8
#define NBLD 1024
#define NSCAT 512

// ---------------- helpers ----------------
__device__ __forceinline__ int rfl(int v) { return __builtin_amdgcn_readfirstlane(v); }

__device__ __forceinline__ int lowerb(const int* a, int n, int v) {
    int lo = 0, hi = n;
    while (lo < hi) { int m = (lo + hi) >> 1; if (a[m] < v) lo = m + 1; else hi = m; }
    return lo;
}

// ---------------- D1: zero [segcnt|bcnt|pooled] + pack W1,W2 fragments -------
__global__ __launch_bounds__(256) void k_pre(int* __restrict__ zbase, int nzero,
        const float* __restrict__ W1, const float* __restrict__ W2,
        _Float16* __restrict__ wfrag) {
    int gidx = blockIdx.x * 256 + threadIdx.x;
    for (int i = gidx; i < nzero; i += NBLD * 256) zbase[i] = 0;
    if (gidx < 32768) {
        const float* W = (gidx < 16384) ? W1 : W2;
        int id = gidx & 16383;
        int j = id & 7, l = (id >> 3) & 63, t = (id >> 9) & 3, nt = id >> 11;
        wfrag[gidx] = (_Float16)W[(t * 32 + (l >> 4) * 8 + j) * 128 + nt * 16 + (l & 15)];
    }
}

// ---------------- D2: bucket edges by dst-range into sub-bucket (w, r) -------
__global__ __launch_bounds__(256) void k_bucket(const int* __restrict__ src,
        const int* __restrict__ dst, int* __restrict__ bcnt, int2* __restrict__ bkt,
        int E, int N, int cap, int csz) {
    __shared__ int sh[16];
    int bid = blockIdx.x;
    int w = bid & (NXCD - 1);
    int e0 = bid * csz, e1 = min(e0 + csz, E);
    int tid = threadIdx.x;
    if (tid < NXCD) sh[tid] = 0;                       // lcnt
    __syncthreads();
    int dd[4], ss[4], rr[4], ll[4];
    #pragma unroll
    for (int it = 0; it < 4; ++it) {
        int e = e0 + it * 256 + tid;
        ll[it] = -1; dd[it] = 0; ss[it] = 0; rr[it] = 0;
        if (e < e1) {
            int d = dst[e], s = src[e];
            int r = (int)(((long long)d << 3) / N);
            dd[it] = d; ss[it] = s; rr[it] = r;
            ll[it] = atomicAdd(&sh[r], 1);
        }
    }
    __syncthreads();
    if (tid < NXCD)                                    // gbase
        sh[8 + tid] = atomicAdd(&bcnt[(w * NXCD + tid) * 16], sh[tid]);
    __syncthreads();
    #pragma unroll
    for (int it = 0; it < 4; ++it)
        if (ll[it] >= 0)
            bkt[(size_t)(w * NXCD + rr[it]) * cap + sh[8 + rr[it]] + ll[it]] =
                make_int2(dd[it], ss[it]);
}

// ---------------- D3: per-(dst, src-slice) histogram from buckets ------------
__global__ __launch_bounds__(256) void k_hist2(const int2* __restrict__ bkt,
        const int* __restrict__ bcnt, int* __restrict__ segcnt, int cap, int N) {
    int x = blockIdx.x & (NXCD - 1);
    int lb = blockIdx.x >> 3, nlb = gridDim.x >> 3;
    for (int w = 0; w < NXCD; ++w) {
        int cnt = rfl(bcnt[(w * NXCD + x) * 16]);
        const int2* b = bkt + (size_t)(w * NXCD + x) * cap;
        for (int i = lb * 256 + threadIdx.x; i < cnt; i += nlb * 256) {
            int2 p = b[i];
            int c = (int)(((long long)p.y << 3) / N);
            atomicAdd(&segcnt[(size_t)p.x * 8 + c], 1);
        }
    }
}

// ---------------- D4: scan1 — deg, dinv, block-local exclusive scan ----------
__global__ __launch_bounds__(256) void k_scan1(const int* __restrict__ segcnt,
        int* __restrict__ locscan, int* __restrict__ bsum, float* __restrict__ dinv, int N) {
    __shared__ int sh[256];
    int t = threadIdx.x;
    int i = blockIdx.x * 256 + t;
    int d = 0;
    if (i < N) {
        const int4* p = (const int4*)(segcnt + (size_t)i * 8);
        int4 a = p[0], b = p[1];
        d = a.x + a.y + a.z + a.w + b.x + b.y + b.z + b.w;
        dinv[i] = rsqrtf((float)d + 1.0f);
    }
    sh[t] = d;
    __syncthreads();
    int v = d;
    #pragma unroll
    for (int o = 1; o < 256; o <<= 1) {
        int u = (t >= o) ? sh[t - o] : 0;
        __syncthreads();
        v += u;
        sh[t] = v;
        __syncthreads();
    }
    if (i < N) locscan[i] = v - d;
    if (t == 255) bsum[blockIdx.x] = v;
}

// ---------------- shared gemm body: Hs[r] = (X W)[r] * dinv[r]  (fp16 out) ---
template <bool AF32>
__device__ __forceinline__ void gemm_body(int bid, int nblocks,
        const void* __restrict__ Xv, const _Float16* __restrict__ wfrag,
        const float* __restrict__ dscale, _Float16* __restrict__ Hh, int nrows) {
    int w = threadIdx.x >> 6, l = threadIdx.x & 63;
    int gw = bid * 4 + w;
    int ch = gw & 1;
    int strip0 = gw >> 1;
    int sstride = nblocks * 2;

    half8 b[4][4];
    #pragma unroll
    for (int q = 0; q < 4; ++q)
        #pragma unroll
        for (int t = 0; t < 4; ++t)
            b[q][t] = *(const half8*)&wfrag[(((ch * 4 + q) * 4 + t) * 64 + l) * 8];

    int row_in = l & 15;
    int kb = l >> 4;
    int nstrips = (nrows + 15) >> 4;
    for (int s = strip0; s < nstrips; s += sstride) {
        int m0 = s << 4;
        int rl = m0 + row_in; if (rl > nrows - 1) rl = nrows - 1;
        half8 a[4];
        if constexpr (AF32) {
            const float* xr = (const float*)Xv + (size_t)rl * 128 + kb * 8;
            #pragma unroll
            for (int t = 0; t < 4; ++t) {
                float4 u0 = *(const float4*)(xr + t * 32);
                float4 u1 = *(const float4*)(xr + t * 32 + 4);
                half8 av = { (_Float16)u0.x, (_Float16)u0.y, (_Float16)u0.z, (_Float16)u0.w,
                             (_Float16)u1.x, (_Float16)u1.y, (_Float16)u1.z, (_Float16)u1.w };
                a[t] = av;
            }
        } else {
            const _Float16* xr = (const _Float16*)Xv + (size_t)rl * 128 + kb * 8;
            #pragma unroll
            for (int t = 0; t < 4; ++t) a[t] = *(const half8*)(xr + t * 32);
        }

        f32x4 acc[4];
        #pragma unroll
        for (int q = 0; q < 4; ++q) acc[q] = (f32x4){0.f, 0.f, 0.f, 0.f};
        #pragma unroll
        for (int t = 0; t < 4; ++t)
            #pragma unroll
            for (int q = 0; q < 4; ++q)
                acc[q] = __builtin_amdgcn_mfma_f32_16x16x32_f16(a[t], b[q][t], acc[q], 0, 0, 0);

        int orow = m0 + (l >> 4) * 4;
        int ocol = ch * 64 + (l & 15);
        _Float16* op = Hh + (size_t)orow * 128 + ocol;
        #pragma unroll
        for (int r = 0; r < 4; ++r) {
            if (orow + r < nrows) {
                float sc = dscale[orow + r];
                #pragma unroll
                for (int q = 0; q < 4; ++q)
                    op[(size_t)r * 128 + q * 16] = (_Float16)(acc[q][r] * sc);
            }
        }
    }
}

// ---------------- D5: scan3b (blocks 0..nb-1) ∥ GEMM layer-1 (rest) ----------
// scan3b is a small coalesced-write pass — safe to co-schedule with the GEMM
// stream (unlike scatter, whose L2-resident dirty lines the stream evicts).
__global__ __launch_bounds__(256, 2) void k_s3g(const int* __restrict__ locscan,
        const int* __restrict__ bsum, const int* __restrict__ segcnt,
        int* __restrict__ off, int* __restrict__ segcur, int N, int nb, int E,
        const float* __restrict__ X, const _Float16* __restrict__ wfrag,
        const float* __restrict__ dinv, _Float16* __restrict__ Hh, int gemm_blocks) {
    __shared__ int sh[256];
    if (blockIdx.x < (unsigned)nb) {
        int t = threadIdx.x;
        int lim = min((int)blockIdx.x, nb);
        sh[t] = (t < lim) ? bsum[t] : 0;
        __syncthreads();
        #pragma unroll
        for (int o = 128; o > 0; o >>= 1) {
            if (t < o) sh[t] += sh[t + o];
            __syncthreads();
        }
        int boff = sh[0];
        int i = blockIdx.x * 256 + t;
        if (i < N) {
            int run = locscan[i] + boff;
            off[i] = run;
            #pragma unroll
            for (int c = 0; c < 8; ++c) {
                segcur[(size_t)i * 8 + c] = run;
                run += segcnt[(size_t)i * 8 + c];
            }
        }
        if (blockIdx.x == 0 && t == 0) off[N] = E;
    } else {
        gemm_body<true>(blockIdx.x - nb, gemm_blocks, (const void*)X, wfrag, dinv, Hh, N);
    }
}

// ---------------- D6: scatter into c-sorted per-dst segments (standalone) ----
__global__ __launch_bounds__(256) void k_scatter_b(const int2* __restrict__ bkt,
        const int* __restrict__ bcnt, int* __restrict__ segcur, int* __restrict__ ssrc,
        int cap, int N) {
    int x = blockIdx.x & (NXCD - 1);
    int lb = blockIdx.x >> 3, nlb = gridDim.x >> 3;
    for (int w = 0; w < NXCD; ++w) {
        int cnt = rfl(bcnt[(w * NXCD + x) * 16]);
        const int2* b = bkt + (size_t)(w * NXCD + x) * cap;
        for (int i = lb * 256 + threadIdx.x; i < cnt; i += nlb * 256) {
            int2 p = b[i];
            int c = (int)(((long long)p.y << 3) / N);
            int pos = atomicAdd(&segcur[(size_t)p.x * 8 + c], 1);
            ssrc[pos] = p.y;
        }
    }
}

// ---------------- layer-2 GEMM (standalone, scaled) ----------------
__global__ __launch_bounds__(256, 2) void k_gemm2(const _Float16* __restrict__ Xh,
        const _Float16* __restrict__ wfrag, const float* __restrict__ dinv,
        _Float16* __restrict__ Hh, int nrows) {
    gemm_body<false>(blockIdx.x, gridDim.x, (const void*)Xh, wfrag, dinv, Hh, nrows);
}

// ---------------- GCN aggregate over pre-scaled Hs: gather + add only --------
// out[d] = relu(dinv[d]*(sum_e Hs[s] + Hs[d]) + bias)
template <int POOL>
__global__ __launch_bounds__(256) void k_agg(const __half* __restrict__ Hh,
        const float* __restrict__ dinv, const int* __restrict__ off,
        const int* __restrict__ ssrc, const float* __restrict__ bias,
        const int* __restrict__ batch, __half* __restrict__ Oh,
        float* __restrict__ pooled, int N) {
    int lane = threadIdx.x & 63;
    int xcd = blockIdx.x & (NXCD - 1);
    int lw  = (blockIdx.x >> 3) * 4 + (threadIdx.x >> 6);
    int nlw = (gridDim.x >> 3) * 4;
    int lo = (int)(((long long)xcd * N) >> 3);
    int hi = (int)(((long long)(xcd + 1) * N) >> 3);
    int run = (hi - lo + nlw - 1) / nlw;
    int i0 = lo + lw * run;
    int i1 = min(i0 + run, hi);
    float2 bv = *(const float2*)&bias[2 * lane];
    float pa0 = 0.f, pa1 = 0.f;
    int cg = -1;
    for (int i = i0; i < i1; ++i) {
        int iu = rfl(i);
        float di = dinv[iu];
        int j0 = rfl(off[iu]);
        int j1 = rfl(off[iu + 1]);
        float2 hv = __half22float2(((const __half2*)(Hh + (size_t)iu * 128))[lane]);
        float a0 = hv.x, a1 = hv.y;     // self term (already scaled by dinv[d])
        int j = j0;
        for (; j + 8 <= j1; j += 8) {
            int s0 = rfl(ssrc[j]),     s1 = rfl(ssrc[j + 1]);
            int s2 = rfl(ssrc[j + 2]), s3 = rfl(ssrc[j + 3]);
            int s4 = rfl(ssrc[j + 4]), s5 = rfl(ssrc[j + 5]);
            int s6 = rfl(ssrc[j + 6]), s7 = rfl(ssrc[j + 7]);
            __half2 g0 = ((const __half2*)(Hh + (size_t)s0 * 128))[lane];
            __half2 g1 = ((const __half2*)(Hh + (size_t)s1 * 128))[lane];
            __half2 g2 = ((const __half2*)(Hh + (size_t)s2 * 128))[lane];
            __half2 g3 = ((const __half2*)(Hh + (size_t)s3 * 128))[lane];
            __half2 g4 = ((const __half2*)(Hh + (size_t)s4 * 128))[lane];
            __half2 g5 = ((const __half2*)(Hh + (size_t)s5 * 128))[lane];
            __half2 g6 = ((const __half2*)(Hh + (size_t)s6 * 128))[lane];
            __half2 g7 = ((const __half2*)(Hh + (size_t)s7 * 128))[lane];
            float2 h;
            h = __half22float2(g0); a0 += h.x; a1 += h.y;
            h = __half22float2(g1); a0 += h.x; a1 += h.y;
            h = __half22float2(g2); a0 += h.x; a1 += h.y;
            h = __half22float2(g3); a0 += h.x; a1 += h.y;
            h = __half22float2(g4); a0 += h.x; a1 += h.y;
            h = __half22float2(g5); a0 += h.x; a1 += h.y;
            h = __half22float2(g6); a0 += h.x; a1 += h.y;
            h = __half22float2(g7); a0 += h.x; a1 += h.y;
        }
        for (; j + 4 <= j1; j += 4) {
            int s0 = rfl(ssrc[j]),     s1 = rfl(ssrc[j + 1]);
            int s2 = rfl(ssrc[j + 2]), s3 = rfl(ssrc[j + 3]);
            __half2 g0 = ((const __half2*)(Hh + (size_t)s0 * 128))[lane];
            __half2 g1 = ((const __half2*)(Hh + (size_t)s1 * 128))[lane];
            __half2 g2 = ((const __half2*)(Hh + (size_t)s2 * 128))[lane];
            __half2 g3 = ((const __half2*)(Hh + (size_t)s3 * 128))[lane];
            float2 h;
            h = __half22float2(g0); a0 += h.x; a1 += h.y;
            h = __half22float2(g1); a0 += h.x; a1 += h.y;
            h = __half22float2(g2); a0 += h.x; a1 += h.y;
            h = __half22float2(g3); a0 += h.x; a1 += h.y;
        }
        for (; j < j1; ++j) {
            int s0 = rfl(ssrc[j]);
            __half2 g0 = ((const __half2*)(Hh + (size_t)s0 * 128))[lane];
            float2 h = __half22float2(g0);
            a0 += h.x; a1 += h.y;
        }
        a0 = fmaxf(fmaf(a0, di, bv.x), 0.f);
        a1 = fmaxf(fmaf(a1, di, bv.y), 0.f);
        if (POOL) {
            int g = rfl(batch[iu]);
            if (g != cg) {
                if (cg >= 0) {
                    atomicAdd(&pooled[cg * 128 + 2 * lane], pa0);
                    atomicAdd(&pooled[cg * 128 + 2 * lane + 1], pa1);
                }
                pa0 = 0.f; pa1 = 0.f; cg = g;
            }
            pa0 += a0; pa1 += a1;
        } else {
            ((__half2*)(Oh + (size_t)iu * 128))[lane] = __floats2half2_rn(a0, a1);
        }
    }
    if (POOL && cg >= 0) {
        atomicAdd(&pooled[cg * 128 + 2 * lane], pa0);
        atomicAdd(&pooled[cg * 128 + 2 * lane + 1], pa1);
    }
}

__global__ void k_final(const float* __restrict__ P, const int* __restrict__ batch,
        const float* __restrict__ Wl, const float* __restrict__ bl,
        float* __restrict__ out, int G, int CO, int N) {
    int t = blockIdx.x * blockDim.x + threadIdx.x;
    if (t >= G * CO) return;
    int g = t / CO, o = t % CO;
    int cnt = lowerb(batch, N, g + 1) - lowerb(batch, N, g);
    float inv = cnt > 0 ? 1.0f / (float)cnt : 0.0f;
    float acc = bl[o];
    for (int k = 0; k < 128; ++k) acc += P[g * 128 + k] * inv * Wl[k * CO + o];
    out[t] = acc;
}

// ---------------- launcher ----------------
extern "C" void kernel_launch(void* const* d_in, const int* in_sizes, int n_in,
                              void* d_out, int out_size, void* d_ws, size_t ws_size,
                              hipStream_t stream) {
    const float* x     = (const float*)d_in[0];
    const int*   ei    = (const int*)d_in[1];
    const int*   batch = (const int*)d_in[2];
    const float* W1e   = (const float*)d_in[5];
    const float* b1e   = (const float*)d_in[6];
    const float* W2e   = (const float*)d_in[9];
    const float* b2e   = (const float*)d_in[10];
    const float* Wlin  = (const float*)d_in[11];
    const float* blin  = (const float*)d_in[12];
    float* out = (float*)d_out;

    int N  = in_sizes[0] / 128;
    int E  = in_sizes[1] / 2;
    int CO = in_sizes[12];          // 10
    int G  = out_size / CO;         // 64

    const int* src = ei;
    const int* dst = ei + E;

    int cap = E / 64 + 8192;

    // workspace layout: zeroed region [segcnt | bcnt | pooled] is contiguous
    _Float16* hh  = (_Float16*)d_ws;                 // N*128 fp16 (pre-scaled Hs)
    _Float16* x1h = hh + (size_t)N * 128;            // N*128 fp16
    int2* bkt     = (int2*)(x1h + (size_t)N * 128);  // 64*cap int2
    int* segcnt   = (int*)(bkt + (size_t)64 * cap);  // N*8
    int* bcnt     = segcnt + (size_t)N * 8;          // 1024
    float* pooled = (float*)(bcnt + 1024);           // G*128
    int* off      = (int*)(pooled + (size_t)G * 128);// N+1 (pad 4)
    int* segcur   = off + (N + 4);                   // N*8
    int* ssrc     = segcur + (size_t)N * 8;          // E
    int* locscan  = ssrc + E;                        // N
    int* bsum     = locscan + N;                     // 256
    float* dinv   = (float*)(bsum + 256);            // N
    _Float16* wfrag = (_Float16*)(dinv + N);         // 32768 halves (W1|W2)

    int nb = (N + 255) / 256;                        // 196
    int csz = (E + NBLD - 1) / NBLD;                 // <= 1024 (4 x 256 iters)
    int nzero = N * 8 + 1024 + G * 128;

    int nstrips = (N + 15) / 16;
    int gemm_blocks = (nstrips * 2 + 3) / 4;

    // D1: zero + weight pack
    k_pre<<<NBLD, 256, 0, stream>>>(segcnt, nzero, W1e, W2e, wfrag);
    // D2: bucket
    k_bucket<<<NBLD, 256, 0, stream>>>(src, dst, bcnt, bkt, E, N, cap, csz);
    // D3: per-(dst,c) histogram
    k_hist2<<<512, 256, 0, stream>>>(bkt, bcnt, segcnt, cap, N);
    // D4: scan1 (dinv ready after this)
    k_scan1<<<nb, 256, 0, stream>>>(segcnt, locscan, bsum, dinv, N);
    // D5: scan3b ∥ GEMM layer-1 (epilogue scales rows by dinv)
    k_s3g<<<nb + gemm_blocks, 256, 0, stream>>>(locscan, bsum, segcnt, off, segcur,
                                                N, nb, E, x, wfrag, dinv, hh, gemm_blocks);
    // D6: scatter (standalone — its L2-resident scatter lines stay clean)
    k_scatter_b<<<NSCAT, 256, 0, stream>>>(bkt, bcnt, segcur, ssrc, cap, N);
    // D7: layer-1 aggregate (gather+add only; writes fp16 x1)
    k_agg<0><<<2048, 256, 0, stream>>>((const __half*)hh, dinv, off, ssrc, b1e,
                                       batch, (__half*)x1h, pooled, N);
    // D8: layer-2 GEMM (scaled)
    k_gemm2<<<gemm_blocks, 256, 0, stream>>>(x1h, wfrag + 16384, dinv, hh, N);
    // D9: layer-2 aggregate fused with mean-pool partials
    k_agg<1><<<2048, 256, 0, stream>>>((const __half*)hh, dinv, off, ssrc, b2e,
                                       batch, (__half*)nullptr, pooled, N);
    // D10: classifier
    k_final<<<3, 256, 0, stream>>>(pooled, batch, Wlin, blin, out, G, CO, N);
}

// Round 16
// 188.217 us; speedup vs baseline: 1.0231x; 1.0231x over previous
//
#include <hip/hip_runtime.h>
#include <hip/hip_fp16.h>

typedef _Float16 half8 __attribute__((ext_vector_type(8)));
typedef float f32x4 __attribute__((ext_vector_type(4)));

#define NXCD 8
#define NBLD 1024
#define NSCAT 512

// ---------------- helpers ----------------
__device__ __forceinline__ int rfl(int v) { return __builtin_amdgcn_readfirstlane(v); }

__device__ __forceinline__ int lowerb(const int* a, int n, int v) {
    int lo = 0, hi = n;
    while (lo < hi) { int m = (lo + hi) >> 1; if (a[m] < v) lo = m + 1; else hi = m; }
    return lo;
}

// ---------------- D1: zero [segcnt|bcnt|pooled] + pack W1,W2 fragments -------
__global__ __launch_bounds__(256) void k_pre(int* __restrict__ zbase, int nzero,
        const float* __restrict__ W1, const float* __restrict__ W2,
        _Float16* __restrict__ wfrag) {
    int gidx = blockIdx.x * 256 + threadIdx.x;
    for (int i = gidx; i < nzero; i += NBLD * 256) zbase[i] = 0;
    if (gidx < 32768) {
        const float* W = (gidx < 16384) ? W1 : W2;
        int id = gidx & 16383;
        int j = id & 7, l = (id >> 3) & 63, t = (id >> 9) & 3, nt = id >> 11;
        wfrag[gidx] = (_Float16)W[(t * 32 + (l >> 4) * 8 + j) * 128 + nt * 16 + (l & 15)];
    }
}

// ---------------- D2: bucket edges by dst-range into sub-bucket (w, r) -------
// payload packed u32 = (d<<16)|s  (valid: N=50000 < 65536) — halves bkt traffic
__global__ __launch_bounds__(256) void k_bucket(const int* __restrict__ src,
        const int* __restrict__ dst, int* __restrict__ bcnt, unsigned* __restrict__ bkt,
        int E, int N, int cap, int csz) {
    __shared__ int sh[16];
    int bid = blockIdx.x;
    int w = bid & (NXCD - 1);
    int e0 = bid * csz, e1 = min(e0 + csz, E);
    int tid = threadIdx.x;
    if (tid < NXCD) sh[tid] = 0;                       // lcnt
    __syncthreads();
    unsigned pk[4]; int rr[4], ll[4];
    #pragma unroll
    for (int it = 0; it < 4; ++it) {
        int e = e0 + it * 256 + tid;
        ll[it] = -1; pk[it] = 0; rr[it] = 0;
        if (e < e1) {
            int d = dst[e], s = src[e];
            int r = (int)(((unsigned)d * 8u) / (unsigned)N);
            pk[it] = ((unsigned)d << 16) | (unsigned)s;
            rr[it] = r;
            ll[it] = atomicAdd(&sh[r], 1);
        }
    }
    __syncthreads();
    if (tid < NXCD)                                    // gbase
        sh[8 + tid] = atomicAdd(&bcnt[(w * NXCD + tid) * 16], sh[tid]);
    __syncthreads();
    #pragma unroll
    for (int it = 0; it < 4; ++it)
        if (ll[it] >= 0)
            bkt[(size_t)(w * NXCD + rr[it]) * cap + sh[8 + rr[it]] + ll[it]] = pk[it];
}

// ---------------- D3: per-(dst, src-slice) histogram from buckets ------------
__global__ __launch_bounds__(256) void k_hist2(const unsigned* __restrict__ bkt,
        const int* __restrict__ bcnt, int* __restrict__ segcnt, int cap, int N) {
    int x = blockIdx.x & (NXCD - 1);
    int lb = blockIdx.x >> 3, nlb = gridDim.x >> 3;
    for (int w = 0; w < NXCD; ++w) {
        int cnt = rfl(bcnt[(w * NXCD + x) * 16]);
        const unsigned* b = bkt + (size_t)(w * NXCD + x) * cap;
        for (int i = lb * 256 + threadIdx.x; i < cnt; i += nlb * 256) {
            unsigned p = b[i];
            int d = (int)(p >> 16);
            int s = (int)(p & 0xffffu);
            int c = (int)(((unsigned)s * 8u) / (unsigned)N);
            atomicAdd(&segcnt[(size_t)d * 8 + c], 1);
        }
    }
}

// ---------------- D4: scan1 — deg, dinv, block-local exclusive scan ----------
__global__ __launch_bounds__(256) void k_scan1(const int* __restrict__ segcnt,
        int* __restrict__ locscan, int* __restrict__ bsum, float* __restrict__ dinv, int N) {
    __shared__ int sh[256];
    int t = threadIdx.x;
    int i = blockIdx.x * 256 + t;
    int d = 0;
    if (i < N) {
        const int4* p = (const int4*)(segcnt + (size_t)i * 8);
        int4 a = p[0], b = p[1];
        d = a.x + a.y + a.z + a.w + b.x + b.y + b.z + b.w;
        dinv[i] = rsqrtf((float)d + 1.0f);
    }
    sh[t] = d;
    __syncthreads();
    int v = d;
    #pragma unroll
    for (int o = 1; o < 256; o <<= 1) {
        int u = (t >= o) ? sh[t - o] : 0;
        __syncthreads();
        v += u;
        sh[t] = v;
        __syncthreads();
    }
    if (i < N) locscan[i] = v - d;
    if (t == 255) bsum[blockIdx.x] = v;
}

// ---------------- D5: scan3b — inline block-sum prefix (absorbs scan2) -------
__global__ __launch_bounds__(256) void k_scan3b(const int* __restrict__ locscan,
        const int* __restrict__ bsum, const int* __restrict__ segcnt,
        int* __restrict__ off, int* __restrict__ segcur, int N, int nb, int E) {
    __shared__ int sh[256];
    int t = threadIdx.x;
    int lim = min((int)blockIdx.x, nb);
    sh[t] = (t < lim) ? bsum[t] : 0;
    __syncthreads();
    #pragma unroll
    for (int o = 128; o > 0; o >>= 1) {
        if (t < o) sh[t] += sh[t + o];
        __syncthreads();
    }
    int boff = sh[0];
    int i = blockIdx.x * 256 + t;
    if (i < N) {
        int run = locscan[i] + boff;
        off[i] = run;
        #pragma unroll
        for (int c = 0; c < 8; ++c) {
            segcur[(size_t)i * 8 + c] = run;
            run += segcnt[(size_t)i * 8 + c];
        }
    }
    if (blockIdx.x == 0 && t == 0) off[N] = E;
}

// ---------------- shared gemm body: Hs[r] = (X W)[r] * dinv[r]  (fp16 out) ---
template <bool AF32>
__device__ __forceinline__ void gemm_body(int bid, int nblocks,
        const void* __restrict__ Xv, const _Float16* __restrict__ wfrag,
        const float* __restrict__ dscale, _Float16* __restrict__ Hh, int nrows) {
    int w = threadIdx.x >> 6, l = threadIdx.x & 63;
    int gw = bid * 4 + w;
    int ch = gw & 1;
    int strip0 = gw >> 1;
    int sstride = nblocks * 2;

    half8 b[4][4];
    #pragma unroll
    for (int q = 0; q < 4; ++q)
        #pragma unroll
        for (int t = 0; t < 4; ++t)
            b[q][t] = *(const half8*)&wfrag[(((ch * 4 + q) * 4 + t) * 64 + l) * 8];

    int row_in = l & 15;
    int kb = l >> 4;
    int nstrips = (nrows + 15) >> 4;
    for (int s = strip0; s < nstrips; s += sstride) {
        int m0 = s << 4;
        int rl = m0 + row_in; if (rl > nrows - 1) rl = nrows - 1;
        half8 a[4];
        if constexpr (AF32) {
            const float* xr = (const float*)Xv + (size_t)rl * 128 + kb * 8;
            #pragma unroll
            for (int t = 0; t < 4; ++t) {
                float4 u0 = *(const float4*)(xr + t * 32);
                float4 u1 = *(const float4*)(xr + t * 32 + 4);
                half8 av = { (_Float16)u0.x, (_Float16)u0.y, (_Float16)u0.z, (_Float16)u0.w,
                             (_Float16)u1.x, (_Float16)u1.y, (_Float16)u1.z, (_Float16)u1.w };
                a[t] = av;
            }
        } else {
            const _Float16* xr = (const _Float16*)Xv + (size_t)rl * 128 + kb * 8;
            #pragma unroll
            for (int t = 0; t < 4; ++t) a[t] = *(const half8*)(xr + t * 32);
        }

        f32x4 acc[4];
        #pragma unroll
        for (int q = 0; q < 4; ++q) acc[q] = (f32x4){0.f, 0.f, 0.f, 0.f};
        #pragma unroll
        for (int t = 0; t < 4; ++t)
            #pragma unroll
            for (int q = 0; q < 4; ++q)
                acc[q] = __builtin_amdgcn_mfma_f32_16x16x32_f16(a[t], b[q][t], acc[q], 0, 0, 0);

        int orow = m0 + (l >> 4) * 4;
        int ocol = ch * 64 + (l & 15);
        _Float16* op = Hh + (size_t)orow * 128 + ocol;
        #pragma unroll
        for (int r = 0; r < 4; ++r) {
            if (orow + r < nrows) {
                float sc = dscale[orow + r];
                #pragma unroll
                for (int q = 0; q < 4; ++q)
                    op[(size_t)r * 128 + q * 16] = (_Float16)(acc[q][r] * sc);
            }
        }
    }
}

// ---------------- D6: scatter (blocks 0..NSCAT-1) ∥ GEMM layer-1 (rest) ------
// (round-14 pairing restored: measured best — overlap beats clean-L2 scatter)
__global__ __launch_bounds__(256, 2) void k_sg(const unsigned* __restrict__ bkt,
        const int* __restrict__ bcnt, int* __restrict__ segcur, int* __restrict__ ssrc,
        int cap, int N,
        const float* __restrict__ X, const _Float16* __restrict__ wfrag,
        const float* __restrict__ dinv, _Float16* __restrict__ Hh, int gemm_blocks) {
    if (blockIdx.x < NSCAT) {
        int x = blockIdx.x & (NXCD - 1);
        int lb = blockIdx.x >> 3, nlb = NSCAT >> 3;
        for (int w = 0; w < NXCD; ++w) {
            int cnt = rfl(bcnt[(w * NXCD + x) * 16]);
            const unsigned* b = bkt + (size_t)(w * NXCD + x) * cap;
            for (int i = lb * 256 + threadIdx.x; i < cnt; i += nlb * 256) {
                unsigned p = b[i];
                int d = (int)(p >> 16);
                int s = (int)(p & 0xffffu);
                int c = (int)(((unsigned)s * 8u) / (unsigned)N);
                int pos = atomicAdd(&segcur[(size_t)d * 8 + c], 1);
                ssrc[pos] = s;
            }
        }
    } else {
        gemm_body<true>(blockIdx.x - NSCAT, gemm_blocks, (const void*)X, wfrag, dinv, Hh, N);
    }
}

// ---------------- layer-2 GEMM (standalone, scaled) ----------------
__global__ __launch_bounds__(256, 2) void k_gemm2(const _Float16* __restrict__ Xh,
        const _Float16* __restrict__ wfrag, const float* __restrict__ dinv,
        _Float16* __restrict__ Hh, int nrows) {
    gemm_body<false>(blockIdx.x, gridDim.x, (const void*)Xh, wfrag, dinv, Hh, nrows);
}

// ---------------- GCN aggregate over pre-scaled Hs: 16-deep gather+add -------
// out[d] = relu(dinv[d]*(sum_e Hs[s] + Hs[d]) + bias)
template <int POOL>
__global__ __launch_bounds__(256) void k_agg(const __half* __restrict__ Hh,
        const float* __restrict__ dinv, const int* __restrict__ off,
        const int* __restrict__ ssrc, const float* __restrict__ bias,
        const int* __restrict__ batch, __half* __restrict__ Oh,
        float* __restrict__ pooled, int N) {
    int lane = threadIdx.x & 63;
    int xcd = blockIdx.x & (NXCD - 1);
    int lw  = (blockIdx.x >> 3) * 4 + (threadIdx.x >> 6);
    int nlw = (gridDim.x >> 3) * 4;
    int lo = (int)(((long long)xcd * N) >> 3);
    int hi = (int)(((long long)(xcd + 1) * N) >> 3);
    int run = (hi - lo + nlw - 1) / nlw;
    int i0 = lo + lw * run;
    int i1 = min(i0 + run, hi);
    float2 bv = *(const float2*)&bias[2 * lane];
    float pa0 = 0.f, pa1 = 0.f;
    int cg = -1;
    for (int i = i0; i < i1; ++i) {
        int iu = rfl(i);
        float di = dinv[iu];
        int j0 = rfl(off[iu]);
        int j1 = rfl(off[iu + 1]);
        float2 hv = __half22float2(((const __half2*)(Hh + (size_t)iu * 128))[lane]);
        float a0 = hv.x, a1 = hv.y;     // self term (pre-scaled by dinv[d])
        int j = j0;
        // 16-deep: avg degree 16 -> typical whole list in one issue burst
        for (; j + 16 <= j1; j += 16) {
            int s0 = rfl(ssrc[j]),      s1 = rfl(ssrc[j + 1]);
            int s2 = rfl(ssrc[j + 2]),  s3 = rfl(ssrc[j + 3]);
            int s4 = rfl(ssrc[j + 4]),  s5 = rfl(ssrc[j + 5]);
            int s6 = rfl(ssrc[j + 6]),  s7 = rfl(ssrc[j + 7]);
            int s8 = rfl(ssrc[j + 8]),  s9 = rfl(ssrc[j + 9]);
            int sa = rfl(ssrc[j + 10]), sb = rfl(ssrc[j + 11]);
            int sc = rfl(ssrc[j + 12]), sd = rfl(ssrc[j + 13]);
            int se = rfl(ssrc[j + 14]), sf = rfl(ssrc[j + 15]);
            __half2 g0 = ((const __half2*)(Hh + (size_t)s0 * 128))[lane];
            __half2 g1 = ((const __half2*)(Hh + (size_t)s1 * 128))[lane];
            __half2 g2 = ((const __half2*)(Hh + (size_t)s2 * 128))[lane];
            __half2 g3 = ((const __half2*)(Hh + (size_t)s3 * 128))[lane];
            __half2 g4 = ((const __half2*)(Hh + (size_t)s4 * 128))[lane];
            __half2 g5 = ((const __half2*)(Hh + (size_t)s5 * 128))[lane];
            __half2 g6 = ((const __half2*)(Hh + (size_t)s6 * 128))[lane];
            __half2 g7 = ((const __half2*)(Hh + (size_t)s7 * 128))[lane];
            __half2 g8 = ((const __half2*)(Hh + (size_t)s8 * 128))[lane];
            __half2 g9 = ((const __half2*)(Hh + (size_t)s9 * 128))[lane];
            __half2 ga = ((const __half2*)(Hh + (size_t)sa * 128))[lane];
            __half2 gb = ((const __half2*)(Hh + (size_t)sb * 128))[lane];
            __half2 gc = ((const __half2*)(Hh + (size_t)sc * 128))[lane];
            __half2 gd = ((const __half2*)(Hh + (size_t)sd * 128))[lane];
            __half2 ge = ((const __half2*)(Hh + (size_t)se * 128))[lane];
            __half2 gf = ((const __half2*)(Hh + (size_t)sf * 128))[lane];
            float2 h;
            h = __half22float2(g0); a0 += h.x; a1 += h.y;
            h = __half22float2(g1); a0 += h.x; a1 += h.y;
            h = __half22float2(g2); a0 += h.x; a1 += h.y;
            h = __half22float2(g3); a0 += h.x; a1 += h.y;
            h = __half22float2(g4); a0 += h.x; a1 += h.y;
            h = __half22float2(g5); a0 += h.x; a1 += h.y;
            h = __half22float2(g6); a0 += h.x; a1 += h.y;
            h = __half22float2(g7); a0 += h.x; a1 += h.y;
            h = __half22float2(g8); a0 += h.x; a1 += h.y;
            h = __half22float2(g9); a0 += h.x; a1 += h.y;
            h = __half22float2(ga); a0 += h.x; a1 += h.y;
            h = __half22float2(gb); a0 += h.x; a1 += h.y;
            h = __half22float2(gc); a0 += h.x; a1 += h.y;
            h = __half22float2(gd); a0 += h.x; a1 += h.y;
            h = __half22float2(ge); a0 += h.x; a1 += h.y;
            h = __half22float2(gf); a0 += h.x; a1 += h.y;
        }
        for (; j + 8 <= j1; j += 8) {
            int s0 = rfl(ssrc[j]),     s1 = rfl(ssrc[j + 1]);
            int s2 = rfl(ssrc[j + 2]), s3 = rfl(ssrc[j + 3]);
            int s4 = rfl(ssrc[j + 4]), s5 = rfl(ssrc[j + 5]);
            int s6 = rfl(ssrc[j + 6]), s7 = rfl(ssrc[j + 7]);
            __half2 g0 = ((const __half2*)(Hh + (size_t)s0 * 128))[lane];
            __half2 g1 = ((const __half2*)(Hh + (size_t)s1 * 128))[lane];
            __half2 g2 = ((const __half2*)(Hh + (size_t)s2 * 128))[lane];
            __half2 g3 = ((const __half2*)(Hh + (size_t)s3 * 128))[lane];
            __half2 g4 = ((const __half2*)(Hh + (size_t)s4 * 128))[lane];
            __half2 g5 = ((const __half2*)(Hh + (size_t)s5 * 128))[lane];
            __half2 g6 = ((const __half2*)(Hh + (size_t)s6 * 128))[lane];
            __half2 g7 = ((const __half2*)(Hh + (size_t)s7 * 128))[lane];
            float2 h;
            h = __half22float2(g0); a0 += h.x; a1 += h.y;
            h = __half22float2(g1); a0 += h.x; a1 += h.y;
            h = __half22float2(g2); a0 += h.x; a1 += h.y;
            h = __half22float2(g3); a0 += h.x; a1 += h.y;
            h = __half22float2(g4); a0 += h.x; a1 += h.y;
            h = __half22float2(g5); a0 += h.x; a1 += h.y;
            h = __half22float2(g6); a0 += h.x; a1 += h.y;
            h = __half22float2(g7); a0 += h.x; a1 += h.y;
        }
        for (; j + 4 <= j1; j += 4) {
            int s0 = rfl(ssrc[j]),     s1 = rfl(ssrc[j + 1]);
            int s2 = rfl(ssrc[j + 2]), s3 = rfl(ssrc[j + 3]);
            __half2 g0 = ((const __half2*)(Hh + (size_t)s0 * 128))[lane];
            __half2 g1 = ((const __half2*)(Hh + (size_t)s1 * 128))[lane];
            __half2 g2 = ((const __half2*)(Hh + (size_t)s2 * 128))[lane];
            __half2 g3 = ((const __half2*)(Hh + (size_t)s3 * 128))[lane];
            float2 h;
            h = __half22float2(g0); a0 += h.x; a1 += h.y;
            h = __half22float2(g1); a0 += h.x; a1 += h.y;
            h = __half22float2(g2); a0 += h.x; a1 += h.y;
            h = __half22float2(g3); a0 += h.x; a1 += h.y;
        }
        for (; j < j1; ++j) {
            int s0 = rfl(ssrc[j]);
            __half2 g0 = ((const __half2*)(Hh + (size_t)s0 * 128))[lane];
            float2 h = __half22float2(g0);
            a0 += h.x; a1 += h.y;
        }
        a0 = fmaxf(fmaf(a0, di, bv.x), 0.f);
        a1 = fmaxf(fmaf(a1, di, bv.y), 0.f);
        if (POOL) {
            int g = rfl(batch[iu]);
            if (g != cg) {
                if (cg >= 0) {
                    atomicAdd(&pooled[cg * 128 + 2 * lane], pa0);
                    atomicAdd(&pooled[cg * 128 + 2 * lane + 1], pa1);
                }
                pa0 = 0.f; pa1 = 0.f; cg = g;
            }
            pa0 += a0; pa1 += a1;
        } else {
            ((__half2*)(Oh + (size_t)iu * 128))[lane] = __floats2half2_rn(a0, a1);
        }
    }
    if (POOL && cg >= 0) {
        atomicAdd(&pooled[cg * 128 + 2 * lane], pa0);
        atomicAdd(&pooled[cg * 128 + 2 * lane + 1], pa1);
    }
}

__global__ void k_final(const float* __restrict__ P, const int* __restrict__ batch,
        const float* __restrict__ Wl, const float* __restrict__ bl,
        float* __restrict__ out, int G, int CO, int N) {
    int t = blockIdx.x * blockDim.x + threadIdx.x;
    if (t >= G * CO) return;
    int g = t / CO, o = t % CO;
    int cnt = lowerb(batch, N, g + 1) - lowerb(batch, N, g);
    float inv = cnt > 0 ? 1.0f / (float)cnt : 0.0f;
    float acc = bl[o];
    for (int k = 0; k < 128; ++k) acc += P[g * 128 + k] * inv * Wl[k * CO + o];
    out[t] = acc;
}

// ---------------- launcher ----------------
extern "C" void kernel_launch(void* const* d_in, const int* in_sizes, int n_in,
                              void* d_out, int out_size, void* d_ws, size_t ws_size,
                              hipStream_t stream) {
    const float* x     = (const float*)d_in[0];
    const int*   ei    = (const int*)d_in[1];
    const int*   batch = (const int*)d_in[2];
    const float* W1e   = (const float*)d_in[5];
    const float* b1e   = (const float*)d_in[6];
    const float* W2e   = (const float*)d_in[9];
    const float* b2e   = (const float*)d_in[10];
    const float* Wlin  = (const float*)d_in[11];
    const float* blin  = (const float*)d_in[12];
    float* out = (float*)d_out;

    int N  = in_sizes[0] / 128;
    int E  = in_sizes[1] / 2;
    int CO = in_sizes[12];          // 10
    int G  = out_size / CO;         // 64

    const int* src = ei;
    const int* dst = ei + E;

    int cap = E / 64 + 8192;

    // workspace layout: zeroed region [segcnt | bcnt | pooled] is contiguous
    _Float16* hh  = (_Float16*)d_ws;                 // N*128 fp16 (pre-scaled Hs)
    _Float16* x1h = hh + (size_t)N * 128;            // N*128 fp16
    unsigned* bkt = (unsigned*)(x1h + (size_t)N * 128);  // 64*cap u32 (packed d<<16|s)
    int* segcnt   = (int*)(bkt + (size_t)64 * cap);  // N*8
    int* bcnt     = segcnt + (size_t)N * 8;          // 1024
    float* pooled = (float*)(bcnt + 1024);           // G*128
    int* off      = (int*)(pooled + (size_t)G * 128);// N+1 (pad 4)
    int* segcur   = off + (N + 4);                   // N*8
    int* ssrc     = segcur + (size_t)N * 8;          // E
    int* locscan  = ssrc + E;                        // N
    int* bsum     = locscan + N;                     // 256
    float* dinv   = (float*)(bsum + 256);            // N
    _Float16* wfrag = (_Float16*)(dinv + N);         // 32768 halves (W1|W2)

    int nb = (N + 255) / 256;                        // 196
    int csz = (E + NBLD - 1) / NBLD;                 // <= 1024 (4 x 256 iters)
    int nzero = N * 8 + 1024 + G * 128;

    int nstrips = (N + 15) / 16;
    int gemm_blocks = (nstrips * 2 + 3) / 4;

    // D1: zero + weight pack
    k_pre<<<NBLD, 256, 0, stream>>>(segcnt, nzero, W1e, W2e, wfrag);
    // D2: bucket (u32-packed payload)
    k_bucket<<<NBLD, 256, 0, stream>>>(src, dst, bcnt, bkt, E, N, cap, csz);
    // D3: per-(dst,c) histogram
    k_hist2<<<512, 256, 0, stream>>>(bkt, bcnt, segcnt, cap, N);
    // D4: scan1 (dinv ready after this)
    k_scan1<<<nb, 256, 0, stream>>>(segcnt, locscan, bsum, dinv, N);
    // D5: scan3b
    k_scan3b<<<nb, 256, 0, stream>>>(locscan, bsum, segcnt, off, segcur, N, nb, E);
    // D6: scatter ∥ GEMM layer-1 (round-14 pairing — measured best)
    k_sg<<<NSCAT + gemm_blocks, 256, 0, stream>>>(bkt, bcnt, segcur, ssrc, cap, N,
                                                  x, wfrag, dinv, hh, gemm_blocks);
    // D7: layer-1 aggregate (16-deep gather+add; writes fp16 x1)
    k_agg<0><<<2048, 256, 0, stream>>>((const __half*)hh, dinv, off, ssrc, b1e,
                                       batch, (__half*)x1h, pooled, N);
    // D8: layer-2 GEMM (scaled)
    k_gemm2<<<gemm_blocks, 256, 0, stream>>>(x1h, wfrag + 16384, dinv, hh, N);
    // D9: layer-2 aggregate fused with mean-pool partials
    k_agg<1><<<2048, 256, 0, stream>>>((const __half*)hh, dinv, off, ssrc, b2e,
                                       batch, (__half*)nullptr, pooled, N);
    // D10: classifier
    k_final<<<3, 256, 0, stream>>>(pooled, batch, Wlin, blin, out, G, CO, N);
}

// Round 17
// 150.056 us; speedup vs baseline: 1.2833x; 1.2543x over previous
//
#include <hip/hip_runtime.h>
#include <hip/hip_fp16.h>

typedef _Float16 half8 __attribute__((ext_vector_type(8)));
typedef float f32x4 __attribute__((ext_vector_type(4)));

#define NXCD 8
#define NBLD 1024
#define NR   256      // dst ranges (one k_csr block per range)
#define BPAD 16       // bcnt line padding (ints)
#define CAPR 4096     // per-range LDS edge capacity (mean 3125, 17 sigma)
#define MAXD 200      // max dsts per range (ceil(50000/256)=196)

// ---------------- helpers ----------------
__device__ __forceinline__ int rfl(int v) { return __builtin_amdgcn_readfirstlane(v); }

__device__ __forceinline__ int lowerb(const int* a, int n, int v) {
    int lo = 0, hi = n;
    while (lo < hi) { int m = (lo + hi) >> 1; if (a[m] < v) lo = m + 1; else hi = m; }
    return lo;
}

// ---------------- D1: zero [bcnt|pooled] + pack W1,W2 fragments -------------
__global__ __launch_bounds__(256) void k_pre(int* __restrict__ zbase, int nzero,
        const float* __restrict__ W1, const float* __restrict__ W2,
        _Float16* __restrict__ wfrag) {
    int gidx = blockIdx.x * 256 + threadIdx.x;
    for (int i = gidx; i < nzero; i += NBLD * 256) zbase[i] = 0;
    if (gidx < 32768) {
        const float* W = (gidx < 16384) ? W1 : W2;
        int id = gidx & 16383;
        int j = id & 7, l = (id >> 3) & 63, t = (id >> 9) & 3, nt = id >> 11;
        wfrag[gidx] = (_Float16)W[(t * 32 + (l >> 4) * 8 + j) * 128 + nt * 16 + (l & 15)];
    }
}

// ---------------- shared gemm body (optionally dinv-scaled epilogue) --------
template <bool AF32, bool SCALE>
__device__ __forceinline__ void gemm_body(int bid, int nblocks,
        const void* __restrict__ Xv, const _Float16* __restrict__ wfrag,
        const float* __restrict__ dscale, _Float16* __restrict__ Hh, int nrows) {
    int w = threadIdx.x >> 6, l = threadIdx.x & 63;
    int gw = bid * 4 + w;
    int ch = gw & 1;
    int strip0 = gw >> 1;
    int sstride = nblocks * 2;

    half8 b[4][4];
    #pragma unroll
    for (int q = 0; q < 4; ++q)
        #pragma unroll
        for (int t = 0; t < 4; ++t)
            b[q][t] = *(const half8*)&wfrag[(((ch * 4 + q) * 4 + t) * 64 + l) * 8];

    int row_in = l & 15;
    int kb = l >> 4;
    int nstrips = (nrows + 15) >> 4;
    for (int s = strip0; s < nstrips; s += sstride) {
        int m0 = s << 4;
        int rl = m0 + row_in; if (rl > nrows - 1) rl = nrows - 1;
        half8 a[4];
        if constexpr (AF32) {
            const float* xr = (const float*)Xv + (size_t)rl * 128 + kb * 8;
            #pragma unroll
            for (int t = 0; t < 4; ++t) {
                float4 u0 = *(const float4*)(xr + t * 32);
                float4 u1 = *(const float4*)(xr + t * 32 + 4);
                half8 av = { (_Float16)u0.x, (_Float16)u0.y, (_Float16)u0.z, (_Float16)u0.w,
                             (_Float16)u1.x, (_Float16)u1.y, (_Float16)u1.z, (_Float16)u1.w };
                a[t] = av;
            }
        } else {
            const _Float16* xr = (const _Float16*)Xv + (size_t)rl * 128 + kb * 8;
            #pragma unroll
            for (int t = 0; t < 4; ++t) a[t] = *(const half8*)(xr + t * 32);
        }

        f32x4 acc[4];
        #pragma unroll
        for (int q = 0; q < 4; ++q) acc[q] = (f32x4){0.f, 0.f, 0.f, 0.f};
        #pragma unroll
        for (int t = 0; t < 4; ++t)
            #pragma unroll
            for (int q = 0; q < 4; ++q)
                acc[q] = __builtin_amdgcn_mfma_f32_16x16x32_f16(a[t], b[q][t], acc[q], 0, 0, 0);

        int orow = m0 + (l >> 4) * 4;
        int ocol = ch * 64 + (l & 15);
        _Float16* op = Hh + (size_t)orow * 128 + ocol;
        #pragma unroll
        for (int r = 0; r < 4; ++r) {
            if (orow + r < nrows) {
                float sc = SCALE ? dscale[orow + r] : 1.0f;
                #pragma unroll
                for (int q = 0; q < 4; ++q)
                    op[(size_t)r * 128 + q * 16] = (_Float16)(acc[q][r] * sc);
            }
        }
    }
}

// ---------------- D2: bucket (256 ranges; blocks 0..NBLD-1) ∥ GEMM1 (rest) --
__global__ __launch_bounds__(256, 2) void k_bg(const int* __restrict__ src,
        const int* __restrict__ dst, int* __restrict__ bcnt, unsigned* __restrict__ bkt,
        int E, int N, int cap, int csz,
        const float* __restrict__ X, const _Float16* __restrict__ wfrag,
        _Float16* __restrict__ Hh, int gemm_blocks) {
    __shared__ int sh[2 * NR];     // lcnt | gbase
    if (blockIdx.x < NBLD) {
        int bid = blockIdx.x;
        int w = bid & (NXCD - 1);
        int e0 = bid * csz, e1 = min(e0 + csz, E);
        int tid = threadIdx.x;
        for (int i = tid; i < NR; i += 256) sh[i] = 0;
        __syncthreads();
        unsigned pk[4]; int rr[4], ll[4];
        #pragma unroll
        for (int it = 0; it < 4; ++it) {
            int e = e0 + it * 256 + tid;
            ll[it] = -1; pk[it] = 0; rr[it] = 0;
            if (e < e1) {
                int d = dst[e], s = src[e];
                int r = (int)(((unsigned)d * (unsigned)NR) / (unsigned)N);
                pk[it] = ((unsigned)d << 16) | (unsigned)s;
                rr[it] = r;
                ll[it] = atomicAdd(&sh[r], 1);
            }
        }
        __syncthreads();
        for (int i = tid; i < NR; i += 256) {
            int c = sh[i];
            sh[NR + i] = (c > 0) ? atomicAdd(&bcnt[(w * NR + i) * BPAD], c) : 0;
        }
        __syncthreads();
        #pragma unroll
        for (int it = 0; it < 4; ++it)
            if (ll[it] >= 0)
                bkt[(size_t)(w * NR + rr[it]) * cap + sh[NR + rr[it]] + ll[it]] = pk[it];
    } else {
        gemm_body<true, false>(blockIdx.x - NBLD, gemm_blocks, (const void*)X, wfrag,
                               nullptr, Hh, N);
    }
}

// ---------------- D3: fused CSR build — counting sort in LDS, 1 block/range -
// Produces off[], dinv[], ssrc[] (dst-major, src-slice-sorted). No global
// atomics, coalesced ssrc writes (replaces hist2+scan1+scan3b+scatter).
__global__ __launch_bounds__(256) void k_csr(const unsigned* __restrict__ bkt,
        const int* __restrict__ bcnt, int* __restrict__ off, int* __restrict__ ssrc,
        float* __restrict__ dinv, int N, int E, int cap) {
    __shared__ int cnt[MAXD * 8];
    __shared__ unsigned estage[CAPR];
    __shared__ int sstage[CAPR];
    __shared__ int wofs[9];
    __shared__ int sh256[256];

    int r = blockIdx.x, tid = threadIdx.x;
    int lo = (int)(((long long)r * N + NR - 1) / NR);
    int hi = (int)(((long long)(r + 1) * N + NR - 1) / NR);
    if (hi > N) hi = N;
    int nd = hi - lo;

    // rbase = total edges in ranges r' < r (all writers)
    int acc = 0;
    for (int i = tid; i < 8 * NR; i += 256)
        if ((i & (NR - 1)) < r) acc += bcnt[i * BPAD];
    sh256[tid] = acc;
    __syncthreads();
    for (int o = 128; o > 0; o >>= 1) {
        if (tid < o) sh256[tid] += sh256[tid + o];
        __syncthreads();
    }
    int rbase = sh256[0];
    __syncthreads();

    if (tid == 0) {
        int runw = 0;
        for (int w = 0; w < 8; ++w) { wofs[w] = runw; runw += bcnt[(w * NR + r) * BPAD]; }
        wofs[8] = runw;
    }
    for (int i = tid; i < nd * 8; i += 256) cnt[i] = 0;
    __syncthreads();
    int nloc = wofs[8];

    // pass 1: stage edges in LDS + count per (d_local, c)
    for (int w = 0; w < 8; ++w) {
        int base = wofs[w];
        int cw = wofs[w + 1] - base;
        const unsigned* b = bkt + (size_t)(w * NR + r) * cap;
        for (int i = tid; i < cw; i += 256) {
            unsigned u = b[i];
            estage[base + i] = u;
            int d = (int)(u >> 16), s = (int)(u & 0xffffu);
            int c = (int)(((unsigned)s * 8u) / (unsigned)N);
            atomicAdd(&cnt[(d - lo) * 8 + c], 1);
        }
    }
    __syncthreads();

    // exclusive scan of cnt[0 .. nd*8)
    int tot = nd * 8;
    int chunk = (tot + 255) / 256;
    int b0 = tid * chunk, b1 = min(b0 + chunk, tot);
    int ssum = 0;
    for (int i = b0; i < b1; ++i) ssum += cnt[i];
    sh256[tid] = ssum;
    __syncthreads();
    int v = ssum;
    for (int o = 1; o < 256; o <<= 1) {
        int u = (tid >= o) ? sh256[tid - o] : 0;
        __syncthreads();
        v += u;
        sh256[tid] = v;
        __syncthreads();
    }
    int runp = v - ssum;
    for (int i = b0; i < b1; ++i) { int c0 = cnt[i]; cnt[i] = runp; runp += c0; }
    __syncthreads();

    // off + dinv (before cnt is consumed as cursors)
    for (int dl = tid; dl < nd; dl += 256) {
        int start = cnt[dl * 8];
        int end = (dl == nd - 1) ? nloc : cnt[(dl + 1) * 8];
        off[lo + dl] = rbase + start;
        dinv[lo + dl] = rsqrtf((float)(end - start) + 1.0f);
    }
    if (r == NR - 1 && tid == 0) off[N] = E;
    __syncthreads();

    // pass 2: place srcs via LDS cursors, then coalesced copy-out
    for (int i = tid; i < nloc; i += 256) {
        unsigned u = estage[i];
        int d = (int)(u >> 16), s = (int)(u & 0xffffu);
        int c = (int)(((unsigned)s * 8u) / (unsigned)N);
        int slot = atomicAdd(&cnt[(d - lo) * 8 + c], 1);
        sstage[slot] = s;
    }
    __syncthreads();
    for (int i = tid; i < nloc; i += 256) ssrc[rbase + i] = sstage[i];
}

// ---------------- layer-2 GEMM (standalone, dinv-scaled) ----------------
__global__ __launch_bounds__(256, 2) void k_gemm2(const _Float16* __restrict__ Xh,
        const _Float16* __restrict__ wfrag, const float* __restrict__ dinv,
        _Float16* __restrict__ Hh, int nrows) {
    gemm_body<false, true>(blockIdx.x, gridDim.x, (const void*)Xh, wfrag, dinv, Hh, nrows);
}

// ---------------- GCN aggregate --------------------------------------------
// PRESCALED=0 (H unscaled): a = H[d]*di + sum_e H[s]*dinv[s]; out = relu(a*di+b)
// PRESCALED=1 (H pre-scaled by dinv): a = H[d] + sum_e H[s];  out = relu(a*di+b)
// POOL=1: accumulate relu'd rows into per-graph partials (sorted batch).
template <int POOL, int PRESCALED>
__global__ __launch_bounds__(256) void k_agg(const __half* __restrict__ Hh,
        const float* __restrict__ dinv, const int* __restrict__ off,
        const int* __restrict__ ssrc, const float* __restrict__ bias,
        const int* __restrict__ batch, __half* __restrict__ Oh,
        float* __restrict__ pooled, int N) {
    int lane = threadIdx.x & 63;
    int xcd = blockIdx.x & (NXCD - 1);
    int lw  = (blockIdx.x >> 3) * 4 + (threadIdx.x >> 6);
    int nlw = (gridDim.x >> 3) * 4;
    int lo = (int)(((long long)xcd * N) >> 3);
    int hi = (int)(((long long)(xcd + 1) * N) >> 3);
    int run = (hi - lo + nlw - 1) / nlw;
    int i0 = lo + lw * run;
    int i1 = min(i0 + run, hi);
    float2 bv = *(const float2*)&bias[2 * lane];
    float pa0 = 0.f, pa1 = 0.f;
    int cg = -1;
    for (int i = i0; i < i1; ++i) {
        int iu = rfl(i);
        float di = dinv[iu];
        int j0 = rfl(off[iu]);
        int j1 = rfl(off[iu + 1]);
        float2 hv = __half22float2(((const __half2*)(Hh + (size_t)iu * 128))[lane]);
        float a0, a1;
        if (PRESCALED) { a0 = hv.x; a1 = hv.y; }
        else           { a0 = hv.x * di; a1 = hv.y * di; }
        int j = j0;
        for (; j + 8 <= j1; j += 8) {
            int s0 = rfl(ssrc[j]),     s1 = rfl(ssrc[j + 1]);
            int s2 = rfl(ssrc[j + 2]), s3 = rfl(ssrc[j + 3]);
            int s4 = rfl(ssrc[j + 4]), s5 = rfl(ssrc[j + 5]);
            int s6 = rfl(ssrc[j + 6]), s7 = rfl(ssrc[j + 7]);
            __half2 g0 = ((const __half2*)(Hh + (size_t)s0 * 128))[lane];
            __half2 g1 = ((const __half2*)(Hh + (size_t)s1 * 128))[lane];
            __half2 g2 = ((const __half2*)(Hh + (size_t)s2 * 128))[lane];
            __half2 g3 = ((const __half2*)(Hh + (size_t)s3 * 128))[lane];
            __half2 g4 = ((const __half2*)(Hh + (size_t)s4 * 128))[lane];
            __half2 g5 = ((const __half2*)(Hh + (size_t)s5 * 128))[lane];
            __half2 g6 = ((const __half2*)(Hh + (size_t)s6 * 128))[lane];
            __half2 g7 = ((const __half2*)(Hh + (size_t)s7 * 128))[lane];
            float2 h;
            if (PRESCALED) {
                h = __half22float2(g0); a0 += h.x; a1 += h.y;
                h = __half22float2(g1); a0 += h.x; a1 += h.y;
                h = __half22float2(g2); a0 += h.x; a1 += h.y;
                h = __half22float2(g3); a0 += h.x; a1 += h.y;
                h = __half22float2(g4); a0 += h.x; a1 += h.y;
                h = __half22float2(g5); a0 += h.x; a1 += h.y;
                h = __half22float2(g6); a0 += h.x; a1 += h.y;
                h = __half22float2(g7); a0 += h.x; a1 += h.y;
            } else {
                float m0 = dinv[s0], m1 = dinv[s1], m2 = dinv[s2], m3 = dinv[s3];
                float m4 = dinv[s4], m5 = dinv[s5], m6 = dinv[s6], m7 = dinv[s7];
                h = __half22float2(g0); a0 = fmaf(h.x, m0, a0); a1 = fmaf(h.y, m0, a1);
                h = __half22float2(g1); a0 = fmaf(h.x, m1, a0); a1 = fmaf(h.y, m1, a1);
                h = __half22float2(g2); a0 = fmaf(h.x, m2, a0); a1 = fmaf(h.y, m2, a1);
                h = __half22float2(g3); a0 = fmaf(h.x, m3, a0); a1 = fmaf(h.y, m3, a1);
                h = __half22float2(g4); a0 = fmaf(h.x, m4, a0); a1 = fmaf(h.y, m4, a1);
                h = __half22float2(g5); a0 = fmaf(h.x, m5, a0); a1 = fmaf(h.y, m5, a1);
                h = __half22float2(g6); a0 = fmaf(h.x, m6, a0); a1 = fmaf(h.y, m6, a1);
                h = __half22float2(g7); a0 = fmaf(h.x, m7, a0); a1 = fmaf(h.y, m7, a1);
            }
        }
        for (; j < j1; ++j) {
            int s0 = rfl(ssrc[j]);
            __half2 g0 = ((const __half2*)(Hh + (size_t)s0 * 128))[lane];
            float2 h = __half22float2(g0);
            if (PRESCALED) { a0 += h.x; a1 += h.y; }
            else { float m0 = dinv[s0]; a0 = fmaf(h.x, m0, a0); a1 = fmaf(h.y, m0, a1); }
        }
        a0 = fmaxf(fmaf(a0, di, bv.x), 0.f);
        a1 = fmaxf(fmaf(a1, di, bv.y), 0.f);
        if (POOL) {
            int g = rfl(batch[iu]);
            if (g != cg) {
                if (cg >= 0) {
                    atomicAdd(&pooled[cg * 128 + 2 * lane], pa0);
                    atomicAdd(&pooled[cg * 128 + 2 * lane + 1], pa1);
                }
                pa0 = 0.f; pa1 = 0.f; cg = g;
            }
            pa0 += a0; pa1 += a1;
        } else {
            ((__half2*)(Oh + (size_t)iu * 128))[lane] = __floats2half2_rn(a0, a1);
        }
    }
    if (POOL && cg >= 0) {
        atomicAdd(&pooled[cg * 128 + 2 * lane], pa0);
        atomicAdd(&pooled[cg * 128 + 2 * lane + 1], pa1);
    }
}

__global__ void k_final(const float* __restrict__ P, const int* __restrict__ batch,
        const float* __restrict__ Wl, const float* __restrict__ bl,
        float* __restrict__ out, int G, int CO, int N) {
    int t = blockIdx.x * blockDim.x + threadIdx.x;
    if (t >= G * CO) return;
    int g = t / CO, o = t % CO;
    int cnt = lowerb(batch, N, g + 1) - lowerb(batch, N, g);
    float inv = cnt > 0 ? 1.0f / (float)cnt : 0.0f;
    float acc = bl[o];
    for (int k = 0; k < 128; ++k) acc += P[g * 128 + k] * inv * Wl[k * CO + o];
    out[t] = acc;
}

// ---------------- launcher ----------------
extern "C" void kernel_launch(void* const* d_in, const int* in_sizes, int n_in,
                              void* d_out, int out_size, void* d_ws, size_t ws_size,
                              hipStream_t stream) {
    const float* x     = (const float*)d_in[0];
    const int*   ei    = (const int*)d_in[1];
    const int*   batch = (const int*)d_in[2];
    const float* W1e   = (const float*)d_in[5];
    const float* b1e   = (const float*)d_in[6];
    const float* W2e   = (const float*)d_in[9];
    const float* b2e   = (const float*)d_in[10];
    const float* Wlin  = (const float*)d_in[11];
    const float* blin  = (const float*)d_in[12];
    float* out = (float*)d_out;

    int N  = in_sizes[0] / 128;
    int E  = in_sizes[1] / 2;
    int CO = in_sizes[12];          // 10
    int G  = out_size / CO;         // 64

    const int* src = ei;
    const int* dst = ei + E;

    int cap = 640;                  // per-(w,r) bucket capacity (mean 390, 12.6 sigma)

    // workspace layout: zeroed region [bcnt | pooled] is contiguous
    _Float16* hh  = (_Float16*)d_ws;                 // N*128 fp16
    _Float16* x1h = hh + (size_t)N * 128;            // N*128 fp16
    unsigned* bkt = (unsigned*)(x1h + (size_t)N * 128);  // 8*NR*cap u32
    int* bcnt     = (int*)(bkt + (size_t)8 * NR * cap);  // NR*8*BPAD ints
    float* pooled = (float*)(bcnt + NR * 8 * BPAD);  // G*128
    int* off      = (int*)(pooled + (size_t)G * 128);// N+1 (pad 4)
    int* ssrc     = off + (N + 4);                   // E
    float* dinv   = (float*)(ssrc + E);              // N
    _Float16* wfrag = (_Float16*)(dinv + N);         // 32768 halves (W1|W2)

    int csz = (E + NBLD - 1) / NBLD;                 // <= 1024 (4 x 256 iters)
    int nzero = NR * 8 * BPAD + G * 128;             // bcnt + pooled

    int nstrips = (N + 15) / 16;
    int gemm_blocks = (nstrips * 2 + 3) / 4;

    // D1: zero + weight pack
    k_pre<<<NBLD, 256, 0, stream>>>(bcnt, nzero, W1e, W2e, wfrag);
    // D2: bucket (256 ranges) ∥ GEMM layer-1 (unscaled -> Hu in hh)
    k_bg<<<NBLD + gemm_blocks, 256, 0, stream>>>(src, dst, bcnt, bkt, E, N, cap, csz,
                                                 x, wfrag, hh, gemm_blocks);
    // D3: fused CSR build (counting sort in LDS; off, dinv, ssrc)
    k_csr<<<NR, 256, 0, stream>>>(bkt, bcnt, off, ssrc, dinv, N, E, cap);
    // D4: layer-1 aggregate (per-edge dinv[s]; writes fp16 x1)
    k_agg<0, 0><<<2048, 256, 0, stream>>>((const __half*)hh, dinv, off, ssrc, b1e,
                                          batch, (__half*)x1h, pooled, N);
    // D5: layer-2 GEMM (dinv-scaled epilogue -> Hs2)
    k_gemm2<<<gemm_blocks, 256, 0, stream>>>(x1h, wfrag + 16384, dinv, hh, N);
    // D6: layer-2 aggregate (add-only) fused with mean-pool partials
    k_agg<1, 1><<<2048, 256, 0, stream>>>((const __half*)hh, dinv, off, ssrc, b2e,
                                          batch, (__half*)nullptr, pooled, N);
    // D7: classifier
    k_final<<<3, 256, 0, stream>>>(pooled, batch, Wlin, blin, out, G, CO, N);
}